// Round 3
// baseline (229.876 us; speedup 1.0000x reference)
//
#include <hip/hip_runtime.h>
#include <hip/hip_fp16.h>
#include <stdint.h>

#define M_DIM 64
#define K_DIM 8192
#define N_DIM 28672
#define QGROUP 128

typedef __attribute__((ext_vector_type(4))) float floatx4;
typedef __attribute__((ext_vector_type(8))) _Float16 halfx8;
typedef __attribute__((ext_vector_type(4))) uint32_t uintx4;

// bit_cast via memcpy (works for non-trivially-copyable HIP types)
template <typename T, typename F>
__device__ __forceinline__ T bc(F f) {
  static_assert(sizeof(T) == sizeof(F), "size mismatch");
  T t;
  __builtin_memcpy(&t, &f, sizeof(T));
  return t;
}

// p = two fp16 lanes holding (1024+nib); returns two fp16 of (nib-8)*s
// (1024+nib and 1032 are fp16-exact, same binade -> sub exact; mul RNE =
// exactly the reference's fp16 multiply)
__device__ __forceinline__ uint32_t dq_pair(uint32_t p, uint32_t s2bits) {
  __half2 v = bc<__half2>(p);
  __half2 z = bc<__half2>(0x64086408u);  // (1032, 1032)
  __half2 s = bc<__half2>(s2bits);
  return bc<uint32_t>(__hmul2(__hsub2(v, z), s));
}

// one packed dword (8 nibbles) -> B fragment (8 fp16) for one n, in the
// PERMUTED k-order [0,4,1,5,2,6,3,7]: pair j extracts nibbles (j, j+4) with
// one shift + one v_and_or_b32 (compiler folds (x&m)|g). Apack uses the same
// k-order, so the MFMA contraction is consistent.
__device__ __forceinline__ halfx8 dequant8(uint32_t q, uint32_t s2bits) {
  const uint32_t MM = 0x000F000Fu;
  const uint32_t MG = 0x64006400u;  // fp16(1024) in both halves
  uintx4 r;
  r.x = dq_pair((q & MM) | MG, s2bits);          // k0 | k4
  r.y = dq_pair(((q >> 4) & MM) | MG, s2bits);   // k1 | k5
  r.z = dq_pair(((q >> 8) & MM) | MG, s2bits);   // k2 | k6
  r.w = dq_pair(((q >> 12) & MM) | MG, s2bits);  // k3 | k7
  return bc<halfx8>(r);
}

// A (fp32, 64x8192, fp16-exact) -> fragment-ordered fp16 pack, with the
// SAME within-8 k-permutation [0,4,1,5,2,6,3,7] as dequant8.
// Apack[((t*4+mf)*64 + l)*8 + j] =
//   (f16) A[(l&15)+16*mf][32*t + 8*(l>>4) + perm[j]]
__global__ __launch_bounds__(256) void pack_a(const float* __restrict__ A,
                                              _Float16* __restrict__ Apack) {
  const int g = (int)blockIdx.x * 256 + (int)threadIdx.x;  // 0 .. 65535
  const int l = g & 63;
  const int mf = (g >> 6) & 3;
  const int t = g >> 8;
  const int row = (l & 15) + 16 * mf;
  const int k0 = 32 * t + 8 * (l >> 4);
  const float* src = A + (size_t)row * K_DIM + k0;
  floatx4 a0 = *(const floatx4*)src;        // k 0..3
  floatx4 a1 = *(const floatx4*)(src + 4);  // k 4..7
  halfx8 hv;
  hv[0] = (_Float16)a0[0]; hv[1] = (_Float16)a1[0];
  hv[2] = (_Float16)a0[1]; hv[3] = (_Float16)a1[1];
  hv[4] = (_Float16)a0[2]; hv[5] = (_Float16)a1[2];
  hv[6] = (_Float16)a0[3]; hv[7] = (_Float16)a1[3];
  *(halfx8*)(Apack + (size_t)g * 8) = hv;
}

// ONE WAVE PER BLOCK (64 threads). Wave owns a 64m x 64n output tile over
// KSLICE of K. KSPLIT=8 -> 448*8 = 3584 waves = 14/CU = 3.5 waves/SIMD.
// launch_bounds(64,4) caps regs at 128 so all are co-resident; latency is
// hidden by TLP (3.5 waves) + a 2-deep q prefetch. No LDS, no barriers.
template <int KSLICE, bool SPLIT, bool PACKED>
__global__ __launch_bounds__(64, 4) void wq_mfma(
    const float* __restrict__ A,        // fp32 raw (only used if !PACKED)
    const _Float16* __restrict__ Apack, // fragment-ordered fp16
    const int* __restrict__ qweight,    // int32, K/8 x N
    const float* __restrict__ scales,   // fp32, K/128 x N (fp16-exact)
    const float* __restrict__ bias,     // fp32, N (fp16-exact)
    float* __restrict__ part,           // KSPLIT x M x N (fp32)
    float* __restrict__ out) {          // fp32, M x N
  constexpr int STEPS = KSLICE / 32;
  constexpr int GROUPS = KSLICE / QGROUP;

  const int l = (int)threadIdx.x & 63;
  const int l15 = l & 15;
  const int l4 = l >> 4;
  const int nb = (int)blockIdx.x * 64;
  const int kb = (int)blockIdx.y * KSLICE;
  const int ncol = nb + 4 * l15;  // lane's first n (4 interleaved via d)

  const int* qptr = qweight + (size_t)((kb >> 3) + l4) * N_DIM + ncol;
  const float* sptr = scales + (size_t)(kb / QGROUP) * N_DIM + ncol;
  // per-step stride 2048 halves (4 KB); mf at +512 halves (imm offset)
  const _Float16* apt = Apack + ((size_t)(kb >> 5) * 256 + l) * 8;
  // raw-A fallback base (row l15, k = kb + 8*l4); mf at +16 rows
  const float* araw = A + (size_t)l15 * K_DIM + (kb + 8 * l4);

  floatx4 acc[4][4];
#pragma unroll
  for (int i = 0; i < 4; ++i)
#pragma unroll
    for (int j = 0; j < 4; ++j) acc[i][j] = (floatx4)(0.0f);

  // q prefetch: 2 steps in flight
  uintx4 q0 = *(const uintx4*)qptr;
  qptr += 4 * (size_t)N_DIM;
  uintx4 q1 = (STEPS > 1) ? *(const uintx4*)qptr : q0;
  qptr += 4 * (size_t)N_DIM;
  floatx4 scv = *(const floatx4*)sptr;
  sptr += N_DIM;

  for (int g = 0; g < GROUPS; ++g) {
    uint32_t s2b[4];
#pragma unroll
    for (int d = 0; d < 4; ++d) {
      unsigned short sb = bc<unsigned short>((_Float16)scv[d]);  // exact
      uint32_t u = (uint32_t)sb;
      s2b[d] = u | (u << 16);  // fp16x2 splat (shift+or, no 32-bit mul)
    }
    floatx4 scn = scv;
    if (g + 1 < GROUPS) scn = *(const floatx4*)sptr;
    sptr += N_DIM;
#pragma unroll
    for (int tt = 0; tt < 4; ++tt) {
      const int t = g * 4 + tt;
      // A fragments for THIS step (L1/L2-resident Apack; 4 x dwordx4).
      // Issued first so the vmcnt wait overlaps the dequant VALU below.
      halfx8 afr[4];
      if constexpr (PACKED) {
#pragma unroll
        for (int mf = 0; mf < 4; ++mf)
          afr[mf] = *(const halfx8*)(apt + mf * 512);
        apt += 2048;
      } else {
#pragma unroll
        for (int mf = 0; mf < 4; ++mf) {
          const float* s0 = araw + (size_t)mf * 16 * K_DIM + (size_t)t * 32;
          floatx4 a0 = *(const floatx4*)s0;
          floatx4 a1 = *(const floatx4*)(s0 + 4);
          afr[mf][0] = (_Float16)a0[0]; afr[mf][1] = (_Float16)a1[0];
          afr[mf][2] = (_Float16)a0[1]; afr[mf][3] = (_Float16)a1[1];
          afr[mf][4] = (_Float16)a0[2]; afr[mf][5] = (_Float16)a1[2];
          afr[mf][6] = (_Float16)a0[3]; afr[mf][7] = (_Float16)a1[3];
        }
      }
      // q prefetch for step t+2
      uintx4 qn = q1;
      if (t + 2 < STEPS) qn = *(const uintx4*)qptr;
      qptr += 4 * (size_t)N_DIM;

      // d-major: keep the B fragment's live range short (4 VGPRs)
#pragma unroll
      for (int d = 0; d < 4; ++d) {
        halfx8 b = dequant8(q0[d], s2b[d]);
#pragma unroll
        for (int mf = 0; mf < 4; ++mf)
          acc[mf][d] = __builtin_amdgcn_mfma_f32_16x16x32_f16(afr[mf], b,
                                                              acc[mf][d], 0, 0, 0);
      }
      q0 = q1;
      q1 = qn;
    }
    scv = scn;
  }

  // Epilogue. C layout: row = 4*l4 + reg (+16*mf), col = l&15; fragment d's
  // col c is global n = nb + 4*c + d -> 4 fragments at fixed (mf, r) are 4
  // consecutive n. Output is FP32.
  if (SPLIT) {
    float* pbase = part + (size_t)blockIdx.y * ((size_t)M_DIM * N_DIM);
#pragma unroll
    for (int mf = 0; mf < 4; ++mf) {
#pragma unroll
      for (int r = 0; r < 4; ++r) {
        const int m = mf * 16 + l4 * 4 + r;
        floatx4 v = {acc[mf][0][r], acc[mf][1][r], acc[mf][2][r], acc[mf][3][r]};
        *(floatx4*)(pbase + (size_t)m * N_DIM + ncol) = v;
      }
    }
  } else {
    floatx4 bb = *(const floatx4*)(bias + ncol);
#pragma unroll
    for (int mf = 0; mf < 4; ++mf) {
#pragma unroll
      for (int r = 0; r < 4; ++r) {
        const int m = mf * 16 + l4 * 4 + r;
        floatx4 v = {acc[mf][0][r] + bb.x, acc[mf][1][r] + bb.y,
                     acc[mf][2][r] + bb.z, acc[mf][3][r] + bb.w};
        *(floatx4*)(out + (size_t)m * N_DIM + ncol) = v;
      }
    }
  }
}

// Sum KS fp32 partials, add fp32 bias, emit fp32.
template <int KS>
__global__ __launch_bounds__(256) void wq_reduce(const float* __restrict__ part,
                                                 const float* __restrict__ bias,
                                                 float* __restrict__ out) {
  const int idx = (int)blockIdx.x * 256 + (int)threadIdx.x;  // over M*N/4
  const int m = idx / (N_DIM / 4);
  const int n = (idx - m * (N_DIM / 4)) * 4;
  floatx4 s = (floatx4)(0.0f);
#pragma unroll
  for (int p = 0; p < KS; ++p)
    s += *(const floatx4*)(part + ((size_t)p * M_DIM + m) * N_DIM + n);
  floatx4 bb = *(const floatx4*)(bias + n);
  s += bb;
  *(floatx4*)(out + (size_t)m * N_DIM + n) = s;
}

extern "C" void kernel_launch(void* const* d_in, const int* in_sizes, int n_in,
                              void* d_out, int out_size, void* d_ws, size_t ws_size,
                              hipStream_t stream) {
  const float* A = (const float*)d_in[0];    // fp32 (64x8192), fp16-exact
  const int* qw = (const int*)d_in[1];       // int32 (1024x28672)
  const float* sc = (const float*)d_in[2];   // fp32 (64x28672), fp16-exact
  const float* bi = (const float*)d_in[3];   // fp32 (28672), fp16-exact
  float* out = (float*)d_out;                // fp32 (64x28672)

  char* ws = (char*)d_ws;
  const size_t packB = (size_t)M_DIM * K_DIM * sizeof(_Float16);  // 1 MiB
  const size_t mnB = (size_t)M_DIM * N_DIM * sizeof(float);       // 7.34 MB
  _Float16* Apack = (_Float16*)ws;
  float* part = (float*)(ws + packB);

  const int nblk = N_DIM / 64;                 // 448 (1-wave blocks)
  const int rblk = (M_DIM * N_DIM / 4) / 256;  // 1792

  if (ws_size >= packB + 8 * mnB) {
    pack_a<<<256, 256, 0, stream>>>(A, Apack);
    wq_mfma<K_DIM / 8, true, true><<<dim3(nblk, 8), 64, 0, stream>>>(
        A, Apack, qw, sc, bi, part, out);
    wq_reduce<8><<<rblk, 256, 0, stream>>>(part, bi, out);
  } else if (ws_size >= packB + 4 * mnB) {
    pack_a<<<256, 256, 0, stream>>>(A, Apack);
    wq_mfma<K_DIM / 4, true, true><<<dim3(nblk, 4), 64, 0, stream>>>(
        A, Apack, qw, sc, bi, part, out);
    wq_reduce<4><<<rblk, 256, 0, stream>>>(part, bi, out);
  } else if (ws_size >= packB + 2 * mnB) {
    pack_a<<<256, 256, 0, stream>>>(A, Apack);
    wq_mfma<K_DIM / 2, true, true><<<dim3(nblk, 2), 64, 0, stream>>>(
        A, Apack, qw, sc, bi, part, out);
    wq_reduce<2><<<rblk, 256, 0, stream>>>(part, bi, out);
  } else if (ws_size >= packB) {
    pack_a<<<256, 256, 0, stream>>>(A, Apack);
    wq_mfma<K_DIM, false, true><<<dim3(nblk, 1), 64, 0, stream>>>(
        A, Apack, qw, sc, bi, part, out);
  } else {
    wq_mfma<K_DIM, false, false><<<dim3(nblk, 1), 64, 0, stream>>>(
        A, (const _Float16*)nullptr, qw, sc, bi, part, out);
  }
}